// Round 1
// baseline (196.479 us; speedup 1.0000x reference)
//
#include <hip/hip_runtime.h>

#define BB 16
#define TT 4096
#define DDIM 512
#define KK 128
#define TC 64              // t-rows per chunk
#define DTILE 64           // d-tile for GEMM
#define NC (TT / TC)       // 64 chunks
#define PI_F 3.14159265358979323846f

// ---------------- kernel 0: sigma + per-k params ----------------
__global__ __launch_bounds__(256) void k_params(
    const float* __restrict__ W, const float* __restrict__ u_sn,
    const float* __restrict__ s_real_raw, const float* __restrict__ s_imag,
    const float* __restrict__ bias, const float* __restrict__ b_log,
    float* __restrict__ params) {
  __shared__ float su[KK];
  __shared__ float sv[DDIM];
  __shared__ float red[4];
  __shared__ float s_sig;
  int tid = threadIdx.x;
  if (tid < KK) su[tid] = u_sn[tid];
  __syncthreads();
  // v = W^T u  (each thread: d = tid, tid+256)
  for (int rep = 0; rep < 2; ++rep) {
    int d = tid + rep * 256;
    float acc = 0.f;
    for (int k = 0; k < KK; ++k) acc += W[k * DDIM + d] * su[k];
    sv[d] = acc;
  }
  __syncthreads();
  // ||v||^2
  float nn = 0.f;
  for (int rep = 0; rep < 2; ++rep) { float v = sv[tid + rep * 256]; nn += v * v; }
  for (int off = 32; off > 0; off >>= 1) nn += __shfl_down(nn, off, 64);
  if ((tid & 63) == 0) red[tid >> 6] = nn;
  __syncthreads();
  float vn2 = red[0] + red[1] + red[2] + red[3];
  __syncthreads();
  float vinv = 1.f / (sqrtf(vn2) + 1e-6f);
  for (int rep = 0; rep < 2; ++rep) sv[tid + rep * 256] *= vinv;
  __syncthreads();
  // Wv per k (threads 0..127), then ||Wv||^2
  float wv = 0.f;
  if (tid < KK) {
    const float* wrow = W + (size_t)tid * DDIM;
    for (int d = 0; d < DDIM; ++d) wv += wrow[d] * sv[d];
  }
  float q = wv * wv;
  for (int off = 32; off > 0; off >>= 1) q += __shfl_down(q, off, 64);
  if ((tid & 63) == 0) red[tid >> 6] = q;
  __syncthreads();
  if (tid == 0) {
    float wn2 = red[0] + red[1] + red[2] + red[3];
    s_sig = wn2 / (sqrtf(wn2) + 1e-6f);
  }
  __syncthreads();
  if (tid < KK) {
    float inv_sigma = 1.f / s_sig;
    float sr = s_real_raw[tid];
    float alpha = ((sr > 20.f) ? sr : log1pf(expf(sr))) + 1e-6f;
    float om = fminf(fmaxf(s_imag[tid], -PI_F), PI_F);
    float bg = expf(b_log[tid]);
    params[tid] = alpha;
    params[KK + tid] = om;
    params[2 * KK + tid] = bg * inv_sigma;   // multiplies raw gemm g
    params[3 * KK + tid] = bg * bias[tid];   // constant term
  }
}

// ---------------- kernel 0b: ct = inclusive cumsum of dt per b ----------------
__global__ __launch_bounds__(256) void k_ct(const float* __restrict__ dt,
                                            float* __restrict__ ct) {
  __shared__ float sc[256];
  int b = blockIdx.x, tid = threadIdx.x;
  const float* row = dt + (size_t)b * TT;
  float* orow = ct + (size_t)b * TT;
  float loc[16];
  float s = 0.f;
  int base = tid * 16;
  for (int i = 0; i < 16; ++i) { s += row[base + i]; loc[i] = s; }
  sc[tid] = s;
  __syncthreads();
  for (int off = 1; off < 256; off <<= 1) {
    float v = (tid >= off) ? sc[tid - off] : 0.f;
    __syncthreads();
    sc[tid] += v;
    __syncthreads();
  }
  float excl = sc[tid] - s;
  for (int i = 0; i < 16; ++i) orow[base + i] = excl + loc[i];
}

// ---------------- kernel 1: GEMM + A-transform + chunk-local scan ----------------
// writes local cumsum w into out (re at [k], im at [K+k]) and chunk totals to csum
__global__ __launch_bounds__(256) void k_gemm_scan(
    const float* __restrict__ x, const float* __restrict__ W,
    const float* __restrict__ dt, const float* __restrict__ ct,
    const float* __restrict__ params, float* __restrict__ out,
    float* __restrict__ csum_re, float* __restrict__ csum_im) {
  __shared__ __align__(16) float smem[TC * DTILE + DTILE * (KK + 4)];  // 50 KB
  float* xs = smem;                    // [TC][DTILE]
  float* wt = smem + TC * DTILE;       // [DTILE][KK+4]  (W transposed)
  int chunk = blockIdx.x, b = blockIdx.y;
  int tid = threadIdx.x;
  int tx = tid & 31, ty = tid >> 5;    // tx: 32 x 4k, ty: 8 x 8t
  int t0 = chunk * TC;
  int k4 = tx * 4;
  float acc[8][4];
#pragma unroll
  for (int i = 0; i < 8; ++i)
#pragma unroll
    for (int c = 0; c < 4; ++c) acc[i][c] = 0.f;

  int lr = tid >> 4;          // 0..15
  int lc = (tid & 15) * 4;    // 0..60
  for (int d0 = 0; d0 < DDIM; d0 += DTILE) {
#pragma unroll
    for (int p = 0; p < 4; ++p) {  // x tile: 64 rows x 64 cols
      int r = p * 16 + lr;
      float4 v = *(const float4*)&x[((size_t)b * TT + t0 + r) * DDIM + d0 + lc];
      *(float4*)&xs[r * DTILE + lc] = v;
    }
#pragma unroll
    for (int p = 0; p < 8; ++p) {  // W tile transposed: wt[d][k] = W[k][d]
      int kk = p * 16 + lr;
      float4 v = *(const float4*)&W[(size_t)kk * DDIM + d0 + lc];
      wt[(lc + 0) * (KK + 4) + kk] = v.x;
      wt[(lc + 1) * (KK + 4) + kk] = v.y;
      wt[(lc + 2) * (KK + 4) + kk] = v.z;
      wt[(lc + 3) * (KK + 4) + kk] = v.w;
    }
    __syncthreads();
#pragma unroll 4
    for (int dd = 0; dd < DTILE; dd += 4) {
      float4 xv[8];
#pragma unroll
      for (int i = 0; i < 8; ++i)
        xv[i] = *(const float4*)&xs[(ty * 8 + i) * DTILE + dd];
      float4 wv0 = *(const float4*)&wt[(dd + 0) * (KK + 4) + k4];
      float4 wv1 = *(const float4*)&wt[(dd + 1) * (KK + 4) + k4];
      float4 wv2 = *(const float4*)&wt[(dd + 2) * (KK + 4) + k4];
      float4 wv3 = *(const float4*)&wt[(dd + 3) * (KK + 4) + k4];
#pragma unroll
      for (int i = 0; i < 8; ++i) {
        float4 xi = xv[i];
        acc[i][0] += xi.x * wv0.x + xi.y * wv1.x + xi.z * wv2.x + xi.w * wv3.x;
        acc[i][1] += xi.x * wv0.y + xi.y * wv1.y + xi.z * wv2.y + xi.w * wv3.y;
        acc[i][2] += xi.x * wv0.z + xi.y * wv1.z + xi.z * wv2.z + xi.w * wv3.z;
        acc[i][3] += xi.x * wv0.w + xi.y * wv1.w + xi.z * wv2.w + xi.w * wv3.w;
      }
    }
    __syncthreads();
  }

  // ---- epilogue: g -> A, thread-local inclusive scan over this thread's 8 t's
  float al[4], om[4], c1[4], c2[4];
  {
    float4 a4 = *(const float4*)&params[k4];
    float4 o4 = *(const float4*)&params[KK + k4];
    float4 g4 = *(const float4*)&params[2 * KK + k4];
    float4 b4 = *(const float4*)&params[3 * KK + k4];
    al[0] = a4.x; al[1] = a4.y; al[2] = a4.z; al[3] = a4.w;
    om[0] = o4.x; om[1] = o4.y; om[2] = o4.z; om[3] = o4.w;
    c1[0] = g4.x; c1[1] = g4.y; c1[2] = g4.z; c1[3] = g4.w;
    c2[0] = b4.x; c2[1] = b4.y; c2[2] = b4.z; c2[3] = b4.w;
  }
  float wre[8][4], wim[8][4];
  float runre[4] = {0.f, 0.f, 0.f, 0.f}, runim[4] = {0.f, 0.f, 0.f, 0.f};
#pragma unroll
  for (int i = 0; i < 8; ++i) {
    int t = t0 + ty * 8 + i;
    float dtv = dt[(size_t)b * TT + t];
    float ctv = ct[(size_t)b * TT + t];
#pragma unroll
    for (int c = 0; c < 4; ++c) {
      float a = al[c] * dtv;                                   // <= ~9.3e-5
      float omr = a * (1.f - a * (0.5f - a * (1.f / 6.f)));    // 1 - exp(-a), exact-ish
      float it = omr * (c1[c] * acc[i][c] + c2[c]);
      float e = __expf(al[c] * ctv);
      float sn, cs;
      __sincosf(om[c] * ctv, &sn, &cs);
      runre[c] += it * e * cs;
      runim[c] -= it * e * sn;
      wre[i][c] = runre[c];
      wim[i][c] = runim[c];
    }
  }
  // ---- cross-ty scan via LDS (alias xs region; safe after the loop's last sync)
  float* totre = smem;          // [8][KK]
  float* totim = smem + 8 * KK; // [8][KK]
#pragma unroll
  for (int c = 0; c < 4; ++c) {
    totre[ty * KK + k4 + c] = runre[c];
    totim[ty * KK + k4 + c] = runim[c];
  }
  __syncthreads();
  float prere[4] = {0.f, 0.f, 0.f, 0.f}, preim[4] = {0.f, 0.f, 0.f, 0.f};
  for (int t2 = 0; t2 < ty; ++t2)
#pragma unroll
    for (int c = 0; c < 4; ++c) {
      prere[c] += totre[t2 * KK + k4 + c];
      preim[c] += totim[t2 * KK + k4 + c];
    }
  if (ty == 7) {
#pragma unroll
    for (int c = 0; c < 4; ++c) {
      csum_re[((size_t)b * NC + chunk) * KK + k4 + c] = prere[c] + runre[c];
      csum_im[((size_t)b * NC + chunk) * KK + k4 + c] = preim[c] + runim[c];
    }
  }
  // ---- write chunk-local inclusive cumsum (with ty-prefix) into out
#pragma unroll
  for (int i = 0; i < 8; ++i) {
    int t = t0 + ty * 8 + i;
    size_t baseo = ((size_t)b * TT + t) * (2 * KK);
    float4 r4 = make_float4(prere[0] + wre[i][0], prere[1] + wre[i][1],
                            prere[2] + wre[i][2], prere[3] + wre[i][3]);
    float4 i4 = make_float4(preim[0] + wim[i][0], preim[1] + wim[i][1],
                            preim[2] + wim[i][2], preim[3] + wim[i][3]);
    *(float4*)&out[baseo + k4] = r4;
    *(float4*)&out[baseo + KK + k4] = i4;
  }
}

// ---------------- kernel 2: exclusive scan over chunk totals ----------------
__global__ __launch_bounds__(128) void k_chunkscan(float* __restrict__ csum_re,
                                                   float* __restrict__ csum_im) {
  int b = blockIdx.x, k = threadIdx.x;
  float runre = 0.f, runim = 0.f;
  for (int c = 0; c < NC; ++c) {
    size_t idx = ((size_t)b * NC + c) * KK + k;
    float vr = csum_re[idx], vi = csum_im[idx];
    csum_re[idx] = runre;
    csum_im[idx] = runim;
    runre += vr;
    runim += vi;
  }
}

// ---------------- kernel 3: add chunk prefix, rotate, emit C and S ----------------
__global__ __launch_bounds__(256) void k_finalize(
    const float* __restrict__ ct, const float* __restrict__ params,
    const float* __restrict__ csum_re, const float* __restrict__ csum_im,
    float* __restrict__ out) {
  int tid = threadIdx.x;
  int tx = tid & 31, ty = tid >> 5;
  int b = blockIdx.y;
  int t = blockIdx.x * 8 + ty;
  int k4 = tx * 4;
  int chunk = t >> 6;  // TC = 64
  float ctv = ct[(size_t)b * TT + t];
  float4 a4 = *(const float4*)&params[k4];
  float4 o4 = *(const float4*)&params[KK + k4];
  size_t baseo = ((size_t)b * TT + t) * (2 * KK);
  float4 wr = *(float4*)&out[baseo + k4];
  float4 wi = *(float4*)&out[baseo + KK + k4];
  size_t cb = ((size_t)b * NC + chunk) * KK + k4;
  float4 pr = *(const float4*)&csum_re[cb];
  float4 pi = *(const float4*)&csum_im[cb];
  float Sre[4] = {wr.x + pr.x, wr.y + pr.y, wr.z + pr.z, wr.w + pr.w};
  float Sim[4] = {wi.x + pi.x, wi.y + pi.y, wi.z + pi.z, wi.w + pi.w};
  float al[4] = {a4.x, a4.y, a4.z, a4.w};
  float om[4] = {o4.x, o4.y, o4.z, o4.w};
  float co[4], so[4];
#pragma unroll
  for (int c = 0; c < 4; ++c) {
    float dec = __expf(-al[c] * ctv);
    float sn, cs;
    __sincosf(om[c] * ctv, &sn, &cs);
    float Rw = dec * (cs * Sre[c] - sn * Sim[c]);
    float Iw = dec * (cs * Sim[c] + sn * Sre[c]);
    co[c] = Rw - Iw;   // C
    so[c] = Rw + Iw;   // S
  }
  *(float4*)&out[baseo + k4] = make_float4(co[0], co[1], co[2], co[3]);
  *(float4*)&out[baseo + KK + k4] = make_float4(so[0], so[1], so[2], so[3]);
}

extern "C" void kernel_launch(void* const* d_in, const int* in_sizes, int n_in,
                              void* d_out, int out_size, void* d_ws, size_t ws_size,
                              hipStream_t stream) {
  const float* x    = (const float*)d_in[0];
  const float* dt   = (const float*)d_in[1];
  const float* srr  = (const float*)d_in[2];
  const float* si   = (const float*)d_in[3];
  const float* W    = (const float*)d_in[4];
  const float* bias = (const float*)d_in[5];
  const float* blog = (const float*)d_in[6];
  const float* usn  = (const float*)d_in[7];
  float* out = (float*)d_out;
  float* ws = (float*)d_ws;

  float* params  = ws;                         // 4*K = 512 floats
  float* ct      = ws + 4 * KK;                // B*T = 65536
  float* csum_re = ct + (size_t)BB * TT;       // B*NC*K = 131072
  float* csum_im = csum_re + (size_t)BB * NC * KK;

  k_params<<<1, 256, 0, stream>>>(W, usn, srr, si, bias, blog, params);
  k_ct<<<BB, 256, 0, stream>>>(dt, ct);
  k_gemm_scan<<<dim3(NC, BB), 256, 0, stream>>>(x, W, dt, ct, params, out,
                                                csum_re, csum_im);
  k_chunkscan<<<BB, KK, 0, stream>>>(csum_re, csum_im);
  k_finalize<<<dim3(TT / 8, BB), 256, 0, stream>>>(ct, params, csum_re, csum_im, out);
}

// Round 2
// 123.440 us; speedup vs baseline: 1.5917x; 1.5917x over previous
//
#include <hip/hip_runtime.h>
#include <stdint.h>

#define BB 16
#define TT 4096
#define DDIM 512
#define KK 128
#define TC 64              // t-rows per chunk
#define NC (TT / TC)       // 64 chunks
#define PI_F 3.14159265358979323846f

typedef unsigned short u16;
typedef __attribute__((ext_vector_type(8))) short short8;
typedef __attribute__((ext_vector_type(4))) float f32x4;

__device__ __forceinline__ uint32_t cvt_bf16_rn(float f) {
  uint32_t u = __float_as_uint(f);
  return (u + 0x7FFFu + ((u >> 16) & 1u)) >> 16;
}
__device__ __forceinline__ void split2(float a, float b, uint32_t& h, uint32_t& l) {
  uint32_t ha = cvt_bf16_rn(a), hb = cvt_bf16_rn(b);
  float ra = a - __uint_as_float(ha << 16);
  float rb = b - __uint_as_float(hb << 16);
  h = ha | (hb << 16);
  l = cvt_bf16_rn(ra) | (cvt_bf16_rn(rb) << 16);
}
__device__ __forceinline__ void split8v(const float4 f0, const float4 f1, uint4& h, uint4& l) {
  split2(f0.x, f0.y, h.x, l.x);
  split2(f0.z, f0.w, h.y, l.y);
  split2(f1.x, f1.y, h.z, l.z);
  split2(f1.z, f1.w, h.w, l.w);
}

// ---------------- kernel 0: sigma + per-k params ----------------
__global__ __launch_bounds__(256) void k_params(
    const float* __restrict__ W, const float* __restrict__ u_sn,
    const float* __restrict__ s_real_raw, const float* __restrict__ s_imag,
    const float* __restrict__ bias, const float* __restrict__ b_log,
    float* __restrict__ params) {
  __shared__ float su[KK];
  __shared__ float sv[DDIM];
  __shared__ float red[4];
  __shared__ float s_sig;
  int tid = threadIdx.x;
  if (tid < KK) su[tid] = u_sn[tid];
  __syncthreads();
  for (int rep = 0; rep < 2; ++rep) {
    int d = tid + rep * 256;
    float acc = 0.f;
    for (int k = 0; k < KK; ++k) acc += W[k * DDIM + d] * su[k];
    sv[d] = acc;
  }
  __syncthreads();
  float nn = 0.f;
  for (int rep = 0; rep < 2; ++rep) { float v = sv[tid + rep * 256]; nn += v * v; }
  for (int off = 32; off > 0; off >>= 1) nn += __shfl_down(nn, off, 64);
  if ((tid & 63) == 0) red[tid >> 6] = nn;
  __syncthreads();
  float vn2 = red[0] + red[1] + red[2] + red[3];
  __syncthreads();
  float vinv = 1.f / (sqrtf(vn2) + 1e-6f);
  for (int rep = 0; rep < 2; ++rep) sv[tid + rep * 256] *= vinv;
  __syncthreads();
  float wv = 0.f;
  if (tid < KK) {
    const float* wrow = W + (size_t)tid * DDIM;
    for (int d = 0; d < DDIM; ++d) wv += wrow[d] * sv[d];
  }
  float q = wv * wv;
  for (int off = 32; off > 0; off >>= 1) q += __shfl_down(q, off, 64);
  if ((tid & 63) == 0) red[tid >> 6] = q;
  __syncthreads();
  if (tid == 0) {
    float wn2 = red[0] + red[1] + red[2] + red[3];
    s_sig = wn2 / (sqrtf(wn2) + 1e-6f);
  }
  __syncthreads();
  if (tid < KK) {
    float inv_sigma = 1.f / s_sig;
    float sr = s_real_raw[tid];
    float alpha = ((sr > 20.f) ? sr : log1pf(expf(sr))) + 1e-6f;
    float om = fminf(fmaxf(s_imag[tid], -PI_F), PI_F);
    float bg = expf(b_log[tid]);
    params[tid] = alpha;
    params[KK + tid] = om;
    params[2 * KK + tid] = bg * inv_sigma;   // multiplies raw gemm g
    params[3 * KK + tid] = bg * bias[tid];   // constant term
  }
}

// ---------------- kernel 0b: ct = inclusive cumsum of dt per b ----------------
__global__ __launch_bounds__(256) void k_ct(const float* __restrict__ dt,
                                            float* __restrict__ ct) {
  __shared__ float sc[256];
  int b = blockIdx.x, tid = threadIdx.x;
  const float* row = dt + (size_t)b * TT;
  float* orow = ct + (size_t)b * TT;
  float loc[16];
  float s = 0.f;
  int base = tid * 16;
  for (int i = 0; i < 16; ++i) { s += row[base + i]; loc[i] = s; }
  sc[tid] = s;
  __syncthreads();
  for (int off = 1; off < 256; off <<= 1) {
    float v = (tid >= off) ? sc[tid - off] : 0.f;
    __syncthreads();
    sc[tid] += v;
    __syncthreads();
  }
  float excl = sc[tid] - s;
  for (int i = 0; i < 16; ++i) orow[base + i] = excl + loc[i];
}

// ---------------- kernel 1: MFMA GEMM + A-transform + chunk-local scan ----------------
// D[k][t] orientation: A = W-tile (bf16 hi/lo), B = x^T-tile (bf16 hi/lo).
// C layout (16x16x32): row=(l>>4)*4+reg -> k, col=l&15 -> t.
__global__ __launch_bounds__(256) void k_gemm_scan(
    const float* __restrict__ x, const float* __restrict__ W,
    const float* __restrict__ dt, const float* __restrict__ ct,
    const float* __restrict__ params, float* __restrict__ out,
    float* __restrict__ csum_re, float* __restrict__ csum_im) {
  __shared__ __align__(16) float smem[12288];   // 48 KB
  u16* xhi = (u16*)&smem[0];       // [64 t][8 slots][8 bf16]
  u16* xlo = (u16*)&smem[2048];
  u16* whi = (u16*)&smem[4096];    // [128 k][8 slots][8 bf16]
  u16* wlo = (u16*)&smem[8192];

  const int chunk = blockIdx.x, b = blockIdx.y;
  const int tid = threadIdx.x;
  const int w = tid >> 6, l = tid & 63;
  const int lm = l & 15, lg = l >> 4;
  const int t0 = chunk * TC;

  const int xr = tid & 63, xc = tid >> 6;      // x staging: row (t), col-group
  const int wrk = tid & 127, wh = tid >> 7;    // W staging: row (k), half
  const size_t xrow_base = ((size_t)b * TT + t0 + xr) * DDIM + xc * 16;
  const size_t wrow_base = (size_t)wrk * DDIM + wh * 32;

  f32x4 acc[2][4];
#pragma unroll
  for (int m = 0; m < 2; ++m)
#pragma unroll
    for (int n = 0; n < 4; ++n) acc[m][n] = (f32x4)(0.0f);

  for (int d0 = 0; d0 < DDIM; d0 += 64) {
    // ---- stage x tile (64 t x 64 d f32 -> bf16 hi/lo, XOR-swizzled 16B slots)
    const float* xp = x + xrow_base + d0;
    float4 xf0 = *(const float4*)(xp + 0);
    float4 xf1 = *(const float4*)(xp + 4);
    float4 xf2 = *(const float4*)(xp + 8);
    float4 xf3 = *(const float4*)(xp + 12);
    // ---- stage W tile (128 k x 64 d)
    const float* wp = W + wrow_base + d0;
    float4 wf[8];
#pragma unroll
    for (int q = 0; q < 8; ++q) wf[q] = *(const float4*)(wp + q * 4);

    uint4 h0, l0, h1, l1;
    split8v(xf0, xf1, h0, l0);
    split8v(xf2, xf3, h1, l1);
    {
      int s0 = ((2 * xc) ^ (xr & 7)) * 8;
      int s1 = ((2 * xc + 1) ^ (xr & 7)) * 8;
      *(uint4*)&xhi[xr * 64 + s0] = h0;
      *(uint4*)&xhi[xr * 64 + s1] = h1;
      *(uint4*)&xlo[xr * 64 + s0] = l0;
      *(uint4*)&xlo[xr * 64 + s1] = l1;
    }
#pragma unroll
    for (int q = 0; q < 4; ++q) {
      uint4 hw, lw;
      split8v(wf[2 * q], wf[2 * q + 1], hw, lw);
      int s = ((wh * 4 + q) ^ (wrk & 7)) * 8;
      *(uint4*)&whi[wrk * 64 + s] = hw;
      *(uint4*)&wlo[wrk * 64 + s] = lw;
    }
    __syncthreads();
    // ---- compute: 2 K-steps of 32
#pragma unroll
    for (int ks = 0; ks < 2; ++ks) {
      int as_ = ((ks * 4 + lg) ^ (lm & 7)) * 8;
      short8 fa_h[2], fa_l[2], fb_h[4], fb_l[4];
#pragma unroll
      for (int m = 0; m < 2; ++m) {
        int row = w * 32 + m * 16 + lm;   // k-row; row&7 == lm&7
        fa_h[m] = *(const short8*)&whi[row * 64 + as_];
        fa_l[m] = *(const short8*)&wlo[row * 64 + as_];
      }
#pragma unroll
      for (int n = 0; n < 4; ++n) {
        int trow = n * 16 + lm;           // t-row; trow&7 == lm&7
        fb_h[n] = *(const short8*)&xhi[trow * 64 + as_];
        fb_l[n] = *(const short8*)&xlo[trow * 64 + as_];
      }
#pragma unroll
      for (int m = 0; m < 2; ++m)
#pragma unroll
        for (int n = 0; n < 4; ++n) {
          acc[m][n] = __builtin_amdgcn_mfma_f32_16x16x32_bf16(fa_h[m], fb_h[n], acc[m][n], 0, 0, 0);
          acc[m][n] = __builtin_amdgcn_mfma_f32_16x16x32_bf16(fa_l[m], fb_h[n], acc[m][n], 0, 0, 0);
          acc[m][n] = __builtin_amdgcn_mfma_f32_16x16x32_bf16(fa_h[m], fb_l[n], acc[m][n], 0, 0, 0);
        }
    }
    __syncthreads();
  }

  // ---- epilogue: params per k-slot (k = w*32 + m*16 + lg*4 + reg)
  float pal[2][4], pom[2][4], pc1[2][4], pc2[2][4];
#pragma unroll
  for (int m = 0; m < 2; ++m) {
    int kb = w * 32 + m * 16 + lg * 4;
    float4 a4 = *(const float4*)&params[kb];
    float4 o4 = *(const float4*)&params[KK + kb];
    float4 g4 = *(const float4*)&params[2 * KK + kb];
    float4 b4 = *(const float4*)&params[3 * KK + kb];
    pal[m][0] = a4.x; pal[m][1] = a4.y; pal[m][2] = a4.z; pal[m][3] = a4.w;
    pom[m][0] = o4.x; pom[m][1] = o4.y; pom[m][2] = o4.z; pom[m][3] = o4.w;
    pc1[m][0] = g4.x; pc1[m][1] = g4.y; pc1[m][2] = g4.z; pc1[m][3] = g4.w;
    pc2[m][0] = b4.x; pc2[m][1] = b4.y; pc2[m][2] = b4.z; pc2[m][3] = b4.w;
  }
  float dtv[4], ctv[4];
#pragma unroll
  for (int n = 0; n < 4; ++n) {
    int t = t0 + n * 16 + lm;
    dtv[n] = dt[(size_t)b * TT + t];
    ctv[n] = ct[(size_t)b * TT + t];
  }
  float wre[2][4][4], wim[2][4][4];
#pragma unroll
  for (int m = 0; m < 2; ++m)
#pragma unroll
    for (int n = 0; n < 4; ++n)
#pragma unroll
      for (int r = 0; r < 4; ++r) {
        float g = acc[m][n][r];
        float a = pal[m][r] * dtv[n];
        float omr = a * (1.f - a * (0.5f - a * (1.f / 6.f)));  // 1 - exp(-a)
        float itv = omr * (pc1[m][r] * g + pc2[m][r]);
        float e = __expf(pal[m][r] * ctv[n]);
        float sn, cs;
        __sincosf(pom[m][r] * ctv[n], &sn, &cs);
        wre[m][n][r] = itv * e * cs;
        wim[m][n][r] = -itv * e * sn;
      }
  // ---- inclusive scan over t: shfl within 16-lane segment, carry across n
#pragma unroll
  for (int m = 0; m < 2; ++m)
#pragma unroll
    for (int r = 0; r < 4; ++r) {
      float cr = 0.f, ci = 0.f;
#pragma unroll
      for (int n = 0; n < 4; ++n) {
        float vr = wre[m][n][r], vi = wim[m][n][r];
#pragma unroll
        for (int d = 1; d < 16; d <<= 1) {
          float ur = __shfl_up(vr, d, 16);
          float ui = __shfl_up(vi, d, 16);
          if (lm >= d) { vr += ur; vi += ui; }
        }
        vr += cr; vi += ci;
        wre[m][n][r] = vr; wim[m][n][r] = vi;
        cr = __shfl(vr, 15, 16);
        ci = __shfl(vi, 15, 16);
      }
      if (lm == 15) {
        int k = w * 32 + m * 16 + lg * 4 + r;
        csum_re[((size_t)b * NC + chunk) * KK + k] = cr;
        csum_im[((size_t)b * NC + chunk) * KK + k] = ci;
      }
    }
  // ---- transpose via LDS, coalesced store (re then im)
  float* tb = smem;  // [64][132]
#pragma unroll
  for (int m = 0; m < 2; ++m)
#pragma unroll
    for (int n = 0; n < 4; ++n)
#pragma unroll
      for (int r = 0; r < 4; ++r)
        tb[(n * 16 + lm) * 132 + w * 32 + m * 16 + lg * 4 + r] = wre[m][n][r];
  __syncthreads();
#pragma unroll
  for (int it = 0; it < 8; ++it) {
    int tr = it * 8 + w * 2 + (l >> 5);
    float4 v = *(const float4*)&tb[tr * 132 + (l & 31) * 4];
    *(float4*)&out[((size_t)b * TT + t0 + tr) * (2 * KK) + (l & 31) * 4] = v;
  }
  __syncthreads();
#pragma unroll
  for (int m = 0; m < 2; ++m)
#pragma unroll
    for (int n = 0; n < 4; ++n)
#pragma unroll
      for (int r = 0; r < 4; ++r)
        tb[(n * 16 + lm) * 132 + w * 32 + m * 16 + lg * 4 + r] = wim[m][n][r];
  __syncthreads();
#pragma unroll
  for (int it = 0; it < 8; ++it) {
    int tr = it * 8 + w * 2 + (l >> 5);
    float4 v = *(const float4*)&tb[tr * 132 + (l & 31) * 4];
    *(float4*)&out[((size_t)b * TT + t0 + tr) * (2 * KK) + KK + (l & 31) * 4] = v;
  }
}

// ---------------- kernel 2: exclusive scan over chunk totals ----------------
__global__ __launch_bounds__(128) void k_chunkscan(float* __restrict__ csum_re,
                                                   float* __restrict__ csum_im) {
  int b = blockIdx.x, k = threadIdx.x;
  float runre = 0.f, runim = 0.f;
  for (int c = 0; c < NC; ++c) {
    size_t idx = ((size_t)b * NC + c) * KK + k;
    float vr = csum_re[idx], vi = csum_im[idx];
    csum_re[idx] = runre;
    csum_im[idx] = runim;
    runre += vr;
    runim += vi;
  }
}

// ---------------- kernel 3: add chunk prefix, rotate, emit C and S ----------------
__global__ __launch_bounds__(256) void k_finalize(
    const float* __restrict__ ct, const float* __restrict__ params,
    const float* __restrict__ csum_re, const float* __restrict__ csum_im,
    float* __restrict__ out) {
  int tid = threadIdx.x;
  int tx = tid & 31, ty = tid >> 5;
  int b = blockIdx.y;
  int t = blockIdx.x * 8 + ty;
  int k4 = tx * 4;
  int chunk = t >> 6;  // TC = 64
  float ctv = ct[(size_t)b * TT + t];
  float4 a4 = *(const float4*)&params[k4];
  float4 o4 = *(const float4*)&params[KK + k4];
  size_t baseo = ((size_t)b * TT + t) * (2 * KK);
  float4 wr = *(float4*)&out[baseo + k4];
  float4 wi = *(float4*)&out[baseo + KK + k4];
  size_t cb = ((size_t)b * NC + chunk) * KK + k4;
  float4 pr = *(const float4*)&csum_re[cb];
  float4 pi = *(const float4*)&csum_im[cb];
  float Sre[4] = {wr.x + pr.x, wr.y + pr.y, wr.z + pr.z, wr.w + pr.w};
  float Sim[4] = {wi.x + pi.x, wi.y + pi.y, wi.z + pi.z, wi.w + pi.w};
  float al[4] = {a4.x, a4.y, a4.z, a4.w};
  float om[4] = {o4.x, o4.y, o4.z, o4.w};
  float co[4], so[4];
#pragma unroll
  for (int c = 0; c < 4; ++c) {
    float dec = __expf(-al[c] * ctv);
    float sn, cs;
    __sincosf(om[c] * ctv, &sn, &cs);
    float Rw = dec * (cs * Sre[c] - sn * Sim[c]);
    float Iw = dec * (cs * Sim[c] + sn * Sre[c]);
    co[c] = Rw - Iw;   // C
    so[c] = Rw + Iw;   // S
  }
  *(float4*)&out[baseo + k4] = make_float4(co[0], co[1], co[2], co[3]);
  *(float4*)&out[baseo + KK + k4] = make_float4(so[0], so[1], so[2], so[3]);
}

extern "C" void kernel_launch(void* const* d_in, const int* in_sizes, int n_in,
                              void* d_out, int out_size, void* d_ws, size_t ws_size,
                              hipStream_t stream) {
  const float* x    = (const float*)d_in[0];
  const float* dt   = (const float*)d_in[1];
  const float* srr  = (const float*)d_in[2];
  const float* si   = (const float*)d_in[3];
  const float* W    = (const float*)d_in[4];
  const float* bias = (const float*)d_in[5];
  const float* blog = (const float*)d_in[6];
  const float* usn  = (const float*)d_in[7];
  float* out = (float*)d_out;
  float* ws = (float*)d_ws;

  float* params  = ws;                         // 4*K = 512 floats
  float* ct      = ws + 4 * KK;                // B*T = 65536
  float* csum_re = ct + (size_t)BB * TT;       // B*NC*K = 131072
  float* csum_im = csum_re + (size_t)BB * NC * KK;

  k_params<<<1, 256, 0, stream>>>(W, usn, srr, si, bias, blog, params);
  k_ct<<<BB, 256, 0, stream>>>(dt, ct);
  k_gemm_scan<<<dim3(NC, BB), 256, 0, stream>>>(x, W, dt, ct, params, out,
                                                csum_re, csum_im);
  k_chunkscan<<<BB, KK, 0, stream>>>(csum_re, csum_im);
  k_finalize<<<dim3(TT / 8, BB), 256, 0, stream>>>(ct, params, csum_re, csum_im, out);
}

// Round 3
// 89.972 us; speedup vs baseline: 2.1838x; 1.3720x over previous
//
#include <hip/hip_runtime.h>
#include <stdint.h>

#define BB 16
#define TT 4096
#define DDIM 512
#define KK 128
#define TCB 128            // t-rows per chunk
#define NCB (TT / TCB)     // 32 chunks
#define PI_F 3.14159265358979323846f

typedef unsigned short u16;
typedef __attribute__((ext_vector_type(8))) short short8;
typedef __attribute__((ext_vector_type(4))) float f32x4;

__device__ __forceinline__ uint32_t cvt_bf16_rn(float f) {
  uint32_t u = __float_as_uint(f);
  return (u + 0x7FFFu + ((u >> 16) & 1u)) >> 16;
}
__device__ __forceinline__ void split2(float a, float b, uint32_t& h, uint32_t& l) {
  uint32_t ha = cvt_bf16_rn(a), hb = cvt_bf16_rn(b);
  float ra = a - __uint_as_float(ha << 16);
  float rb = b - __uint_as_float(hb << 16);
  h = ha | (hb << 16);
  l = cvt_bf16_rn(ra) | (cvt_bf16_rn(rb) << 16);
}
__device__ __forceinline__ void split8v(const float4 f0, const float4 f1, uint4& h, uint4& l) {
  split2(f0.x, f0.y, h.x, l.x);
  split2(f0.z, f0.w, h.y, l.y);
  split2(f1.x, f1.y, h.z, l.z);
  split2(f1.z, f1.w, h.w, l.w);
}
__device__ __forceinline__ void gload_lds16(const void* g, void* l) {
  __builtin_amdgcn_global_load_lds(
      (const __attribute__((address_space(1))) void*)g,
      (__attribute__((address_space(3))) void*)l, 16, 0, 0);
}

// ---------------- kernel 0: sigma + per-k params ----------------
__global__ __launch_bounds__(256) void k_params(
    const float* __restrict__ W, const float* __restrict__ u_sn,
    const float* __restrict__ s_real_raw, const float* __restrict__ s_imag,
    const float* __restrict__ bias, const float* __restrict__ b_log,
    float* __restrict__ params) {
  __shared__ float su[KK];
  __shared__ float sv[DDIM];
  __shared__ float red[4];
  __shared__ float s_sig;
  int tid = threadIdx.x;
  if (tid < KK) su[tid] = u_sn[tid];
  __syncthreads();
  for (int rep = 0; rep < 2; ++rep) {
    int d = tid + rep * 256;
    float acc = 0.f;
    for (int k = 0; k < KK; ++k) acc += W[k * DDIM + d] * su[k];
    sv[d] = acc;
  }
  __syncthreads();
  float nn = 0.f;
  for (int rep = 0; rep < 2; ++rep) { float v = sv[tid + rep * 256]; nn += v * v; }
  for (int off = 32; off > 0; off >>= 1) nn += __shfl_down(nn, off, 64);
  if ((tid & 63) == 0) red[tid >> 6] = nn;
  __syncthreads();
  float vn2 = red[0] + red[1] + red[2] + red[3];
  __syncthreads();
  float vinv = 1.f / (sqrtf(vn2) + 1e-6f);
  for (int rep = 0; rep < 2; ++rep) sv[tid + rep * 256] *= vinv;
  __syncthreads();
  float wv = 0.f;
  if (tid < KK) {
    const float* wrow = W + (size_t)tid * DDIM;
    for (int d = 0; d < DDIM; ++d) wv += wrow[d] * sv[d];
  }
  float q = wv * wv;
  for (int off = 32; off > 0; off >>= 1) q += __shfl_down(q, off, 64);
  if ((tid & 63) == 0) red[tid >> 6] = q;
  __syncthreads();
  if (tid == 0) {
    float wn2 = red[0] + red[1] + red[2] + red[3];
    s_sig = wn2 / (sqrtf(wn2) + 1e-6f);
  }
  __syncthreads();
  if (tid < KK) {
    float inv_sigma = 1.f / s_sig;
    float sr = s_real_raw[tid];
    float alpha = ((sr > 20.f) ? sr : log1pf(expf(sr))) + 1e-6f;
    float om = fminf(fmaxf(s_imag[tid], -PI_F), PI_F);
    float bg = expf(b_log[tid]);
    params[tid] = alpha;
    params[KK + tid] = om;
    params[2 * KK + tid] = bg * inv_sigma;
    params[3 * KK + tid] = bg * bias[tid];
  }
}

// ---------------- kernel 0a: prepack W into bf16 hi/lo LDS images ----------------
// Wp layout per d0-tile (8 tiles): [hi: 8192 u16][lo: 8192 u16];
// image idx = k*64 + ((dl>>3)^(k&7))*8 + (dl&7), dl = d - tile*64.
__global__ __launch_bounds__(256) void k_wpack(const float* __restrict__ W,
                                               u16* __restrict__ Wp) {
  int idx = blockIdx.x * 256 + threadIdx.x;   // 16384 threads, 4 d's each
  int k = idx >> 7;
  int d = (idx & 127) * 4;
  float4 v = *(const float4*)&W[(size_t)k * DDIM + d];
  uint32_t h0, l0, h1, l1;
  split2(v.x, v.y, h0, l0);
  split2(v.z, v.w, h1, l1);
  int tile = d >> 6, dl = d & 63;
  int slot = (dl >> 3) ^ (k & 7);
  int e = dl & 7;  // 0 or 4
  size_t base = (size_t)tile * 16384 + k * 64 + slot * 8 + e;
  *(uint32_t*)&Wp[base] = h0;
  *(uint32_t*)&Wp[base + 2] = h1;
  *(uint32_t*)&Wp[base + 8192] = l0;
  *(uint32_t*)&Wp[base + 8192 + 2] = l1;
}

// ---------------- kernel 0b: ct = inclusive cumsum of dt per b ----------------
__global__ __launch_bounds__(256) void k_ct(const float* __restrict__ dt,
                                            float* __restrict__ ct) {
  __shared__ float sc[256];
  int b = blockIdx.x, tid = threadIdx.x;
  const float* row = dt + (size_t)b * TT;
  float* orow = ct + (size_t)b * TT;
  float loc[16];
  float s = 0.f;
  int base = tid * 16;
  for (int i = 0; i < 16; ++i) { s += row[base + i]; loc[i] = s; }
  sc[tid] = s;
  __syncthreads();
  for (int off = 1; off < 256; off <<= 1) {
    float v = (tid >= off) ? sc[tid - off] : 0.f;
    __syncthreads();
    sc[tid] += v;
    __syncthreads();
  }
  float excl = sc[tid] - s;
  for (int i = 0; i < 16; ++i) orow[base + i] = excl + loc[i];
}

// ---------------- kernel 1: MFMA GEMM + transform + chunk-local scan ----------------
// D[t][k]: A = x-tile (bf16 hi/lo in LDS), B = W-tile (pre-packed, global_load_lds).
// C layout: row = t = (l>>4)*4+reg, col = k = l&15.
__global__ __launch_bounds__(512, 4) void k_gemm_scan(
    const float* __restrict__ x, const u16* __restrict__ Wp,
    const float* __restrict__ dt, const float* __restrict__ ct,
    const float* __restrict__ params, float* __restrict__ out,
    float* __restrict__ csum_re, float* __restrict__ csum_im) {
  __shared__ __align__(16) u16 smem[32768];   // 64 KB
  u16* xhi = smem;            // [128][64]
  u16* xlo = smem + 8192;
  u16* whi = smem + 16384;    // [128][64]
  u16* wlo = smem + 24576;

  const int chunk = blockIdx.x, b = blockIdx.y;
  const int tid = threadIdx.x;
  const int wv = tid >> 6, l = tid & 63;
  const int lm = l & 15, lg = l >> 4;
  const int kw = wv & 1, tw = wv >> 1;
  const int t0 = chunk * TCB;

  const int xr = tid >> 2, xq = (tid & 3) * 16;
  const size_t xbase = ((size_t)b * TT + t0 + xr) * DDIM + xq;
  const char* wsrc0 = (const char*)Wp + (size_t)wv * 1024 + (size_t)l * 16;
  char* wdst0 = (char*)whi + wv * 1024;
  const int xs0 = ((xq >> 3) ^ (xr & 7)) * 8;
  const int xs1 = (((xq >> 3) + 1) ^ (xr & 7)) * 8;

  f32x4 acc[2][4];
#pragma unroll
  for (int m = 0; m < 2; ++m)
#pragma unroll
    for (int n = 0; n < 4; ++n) acc[m][n] = (f32x4)(0.0f);

  for (int d0 = 0; d0 < DDIM; d0 += 64) {
    // W: 4x global_load_lds (pre-swizzled image, zero VALU)
    const char* ws = wsrc0 + (size_t)(d0 >> 6) * 32768;
#pragma unroll
    for (int r = 0; r < 4; ++r)
      gload_lds16(ws + r * 8192, wdst0 + r * 8192);
    // x: load 16 f32, split to bf16 hi/lo, swizzled LDS write
    const float* xp = x + xbase + d0;
    float4 f0 = *(const float4*)(xp + 0);
    float4 f1 = *(const float4*)(xp + 4);
    float4 f2 = *(const float4*)(xp + 8);
    float4 f3 = *(const float4*)(xp + 12);
    uint4 h0, lo0, h1, lo1;
    split8v(f0, f1, h0, lo0);
    split8v(f2, f3, h1, lo1);
    *(uint4*)&xhi[xr * 64 + xs0] = h0;
    *(uint4*)&xhi[xr * 64 + xs1] = h1;
    *(uint4*)&xlo[xr * 64 + xs0] = lo0;
    *(uint4*)&xlo[xr * 64 + xs1] = lo1;
    __syncthreads();
#pragma unroll
    for (int ks = 0; ks < 2; ++ks) {
      short8 fa_h[2], fa_l[2], fb_h[4], fb_l[4];
#pragma unroll
      for (int m = 0; m < 2; ++m) {
        int row = tw * 32 + m * 16 + lm;
        int sw = ((ks * 4 + lg) ^ (row & 7)) * 8;
        fa_h[m] = *(const short8*)&xhi[row * 64 + sw];
        fa_l[m] = *(const short8*)&xlo[row * 64 + sw];
      }
#pragma unroll
      for (int n = 0; n < 4; ++n) {
        int row = kw * 64 + n * 16 + lm;
        int sw = ((ks * 4 + lg) ^ (row & 7)) * 8;
        fb_h[n] = *(const short8*)&whi[row * 64 + sw];
        fb_l[n] = *(const short8*)&wlo[row * 64 + sw];
      }
#pragma unroll
      for (int m = 0; m < 2; ++m)
#pragma unroll
        for (int n = 0; n < 4; ++n) {
          acc[m][n] = __builtin_amdgcn_mfma_f32_16x16x32_bf16(fa_h[m], fb_h[n], acc[m][n], 0, 0, 0);
          acc[m][n] = __builtin_amdgcn_mfma_f32_16x16x32_bf16(fa_l[m], fb_h[n], acc[m][n], 0, 0, 0);
          acc[m][n] = __builtin_amdgcn_mfma_f32_16x16x32_bf16(fa_h[m], fb_l[n], acc[m][n], 0, 0, 0);
        }
    }
    __syncthreads();
  }

  // ---- params per n (k = kw*64 + n*16 + lm), dt/ct per (m,r)
  float pal[4], pom[4], pc1[4], pc2[4];
#pragma unroll
  for (int n = 0; n < 4; ++n) {
    int k = kw * 64 + n * 16 + lm;
    pal[n] = params[k];
    pom[n] = params[KK + k];
    pc1[n] = params[2 * KK + k];
    pc2[n] = params[3 * KK + k];
  }
  float dtv[2][4], ctv[2][4];
#pragma unroll
  for (int m = 0; m < 2; ++m)
#pragma unroll
    for (int r = 0; r < 4; ++r) {
      int t = t0 + tw * 32 + m * 16 + lg * 4 + r;
      dtv[m][r] = dt[(size_t)b * TT + t];
      ctv[m][r] = ct[(size_t)b * TT + t];
    }
  // ---- transform g -> w (complex contribution)
  float vre[2][4][4], vim[2][4][4];
#pragma unroll
  for (int m = 0; m < 2; ++m)
#pragma unroll
    for (int n = 0; n < 4; ++n)
#pragma unroll
      for (int r = 0; r < 4; ++r) {
        float g = acc[m][n][r];
        float a = pal[n] * dtv[m][r];
        float omr = a * (1.f - a * (0.5f - a * (1.f / 6.f)));  // 1 - exp(-a)
        float itv = omr * (pc1[n] * g + pc2[n]);
        float e = __expf(pal[n] * ctv[m][r]);
        float sn, cs;
        __sincosf(pom[n] * ctv[m][r], &sn, &cs);
        vre[m][n][r] = itv * e * cs;
        vim[m][n][r] = -(itv * e) * sn;
      }
  // ---- scan over t within wave: serial r, 2-step lg prefix, chain m
  float carR[4], carI[4];
#pragma unroll
  for (int n = 0; n < 4; ++n) {
    float cr = 0.f, ci = 0.f;
#pragma unroll
    for (int m = 0; m < 2; ++m) {
      vre[m][n][1] += vre[m][n][0];
      vre[m][n][2] += vre[m][n][1];
      vre[m][n][3] += vre[m][n][2];
      vim[m][n][1] += vim[m][n][0];
      vim[m][n][2] += vim[m][n][1];
      vim[m][n][3] += vim[m][n][2];
      float ar = vre[m][n][3], ai = vim[m][n][3];
      float tr = ar, ti = ai;
      float ur = __shfl_up(ar, 16, 64);
      float ui = __shfl_up(ai, 16, 64);
      if (lg >= 1) { ar += ur; ai += ui; }
      ur = __shfl_up(ar, 32, 64);
      ui = __shfl_up(ai, 32, 64);
      if (lg >= 2) { ar += ur; ai += ui; }
      float exr = ar - tr + cr;
      float exi = ai - ti + ci;
#pragma unroll
      for (int r = 0; r < 4; ++r) { vre[m][n][r] += exr; vim[m][n][r] += exi; }
      cr += __shfl(ar, 48 + lm, 64);
      ci += __shfl(ai, 48 + lm, 64);
    }
    carR[n] = cr; carI[n] = ci;
  }
  // ---- cross-wave (tw) carry via LDS
  float* totr = (float*)smem;         // [4][128]
  float* toti = (float*)smem + 4 * KK;
  if (lg == 0)
#pragma unroll
    for (int n = 0; n < 4; ++n) {
      totr[tw * KK + kw * 64 + n * 16 + lm] = carR[n];
      toti[tw * KK + kw * 64 + n * 16 + lm] = carI[n];
    }
  __syncthreads();
  float crR[4] = {0.f, 0.f, 0.f, 0.f}, crI[4] = {0.f, 0.f, 0.f, 0.f};
  for (int t2 = 0; t2 < tw; ++t2)
#pragma unroll
    for (int n = 0; n < 4; ++n) {
      crR[n] += totr[t2 * KK + kw * 64 + n * 16 + lm];
      crI[n] += toti[t2 * KK + kw * 64 + n * 16 + lm];
    }
  if (tw == 3 && lg == 0)
#pragma unroll
    for (int n = 0; n < 4; ++n) {
      int k = kw * 64 + n * 16 + lm;
      csum_re[((size_t)b * NCB + chunk) * KK + k] = crR[n] + carR[n];
      csum_im[((size_t)b * NCB + chunk) * KK + k] = crI[n] + carI[n];
    }
  // ---- direct coalesced-ish store (lanes contiguous over 16 k)
#pragma unroll
  for (int m = 0; m < 2; ++m)
#pragma unroll
    for (int r = 0; r < 4; ++r) {
      size_t rowb = ((size_t)b * TT + t0 + tw * 32 + m * 16 + lg * 4 + r) * (2 * KK);
#pragma unroll
      for (int n = 0; n < 4; ++n) {
        int k = kw * 64 + n * 16 + lm;
        out[rowb + k] = vre[m][n][r] + crR[n];
        out[rowb + KK + k] = vim[m][n][r] + crI[n];
      }
    }
}

// ---------------- kernel 2: exclusive scan over chunk totals ----------------
__global__ __launch_bounds__(128) void k_chunkscan(float* __restrict__ csum_re,
                                                   float* __restrict__ csum_im) {
  int b = blockIdx.x, k = threadIdx.x;
  float runre = 0.f, runim = 0.f;
  for (int c = 0; c < NCB; ++c) {
    size_t idx = ((size_t)b * NCB + c) * KK + k;
    float vr = csum_re[idx], vi = csum_im[idx];
    csum_re[idx] = runre;
    csum_im[idx] = runim;
    runre += vr;
    runim += vi;
  }
}

// ---------------- kernel 3: add chunk prefix, rotate, emit C and S ----------------
__global__ __launch_bounds__(256) void k_finalize(
    const float* __restrict__ ct, const float* __restrict__ params,
    const float* __restrict__ csum_re, const float* __restrict__ csum_im,
    float* __restrict__ out) {
  int tid = threadIdx.x;
  int tx = tid & 31, ty = tid >> 5;
  int b = blockIdx.y;
  int t = blockIdx.x * 8 + ty;
  int k4 = tx * 4;
  int chunk = t >> 7;  // TCB = 128
  float ctv = ct[(size_t)b * TT + t];
  float4 a4 = *(const float4*)&params[k4];
  float4 o4 = *(const float4*)&params[KK + k4];
  size_t baseo = ((size_t)b * TT + t) * (2 * KK);
  float4 wr = *(float4*)&out[baseo + k4];
  float4 wi = *(float4*)&out[baseo + KK + k4];
  size_t cb = ((size_t)b * NCB + chunk) * KK + k4;
  float4 pr = *(const float4*)&csum_re[cb];
  float4 pi = *(const float4*)&csum_im[cb];
  float Sre[4] = {wr.x + pr.x, wr.y + pr.y, wr.z + pr.z, wr.w + pr.w};
  float Sim[4] = {wi.x + pi.x, wi.y + pi.y, wi.z + pi.z, wi.w + pi.w};
  float al[4] = {a4.x, a4.y, a4.z, a4.w};
  float om[4] = {o4.x, o4.y, o4.z, o4.w};
  float co[4], so[4];
#pragma unroll
  for (int c = 0; c < 4; ++c) {
    float dec = __expf(-al[c] * ctv);
    float sn, cs;
    __sincosf(om[c] * ctv, &sn, &cs);
    float Rw = dec * (cs * Sre[c] - sn * Sim[c]);
    float Iw = dec * (cs * Sim[c] + sn * Sre[c]);
    co[c] = Rw - Iw;   // C
    so[c] = Rw + Iw;   // S
  }
  *(float4*)&out[baseo + k4] = make_float4(co[0], co[1], co[2], co[3]);
  *(float4*)&out[baseo + KK + k4] = make_float4(so[0], so[1], so[2], so[3]);
}

extern "C" void kernel_launch(void* const* d_in, const int* in_sizes, int n_in,
                              void* d_out, int out_size, void* d_ws, size_t ws_size,
                              hipStream_t stream) {
  const float* x    = (const float*)d_in[0];
  const float* dt   = (const float*)d_in[1];
  const float* srr  = (const float*)d_in[2];
  const float* si   = (const float*)d_in[3];
  const float* W    = (const float*)d_in[4];
  const float* bias = (const float*)d_in[5];
  const float* blog = (const float*)d_in[6];
  const float* usn  = (const float*)d_in[7];
  float* out = (float*)d_out;
  float* ws = (float*)d_ws;

  float* params  = ws;                          // 512 f
  float* ct      = ws + 4 * KK;                 // 65536 f
  float* csum_re = ct + (size_t)BB * TT;        // 65536 f
  float* csum_im = csum_re + (size_t)BB * NCB * KK;
  u16*   Wp      = (u16*)(csum_im + (size_t)BB * NCB * KK);  // 131072 u16

  k_params<<<1, 256, 0, stream>>>(W, usn, srr, si, bias, blog, params);
  k_wpack<<<64, 256, 0, stream>>>(W, Wp);
  k_ct<<<BB, 256, 0, stream>>>(dt, ct);
  k_gemm_scan<<<dim3(NCB, BB), 512, 0, stream>>>(x, Wp, dt, ct, params, out,
                                                 csum_re, csum_im);
  k_chunkscan<<<BB, KK, 0, stream>>>(csum_re, csum_im);
  k_finalize<<<dim3(TT / 8, BB), 256, 0, stream>>>(ct, params, csum_re, csum_im, out);
}